// Round 1
// baseline (375.053 us; speedup 1.0000x reference)
//
#include <hip/hip_runtime.h>

#define ALPHA 0.65f
#define L 1024
#define BDIM 256
#define KPT 4   // columns per thread: L / BDIM

__global__ __launch_bounds__(BDIM) void bicut_loss_kernel(
    const float* __restrict__ out,     // [B, L, 2]
    const int* __restrict__ labels,    // [B, L]
    float* __restrict__ result)        // scalar
{
    const int row = blockIdx.x;
    const int t = threadIdx.x;

    const float2* rowp = reinterpret_cast<const float2*>(out) + (size_t)row * L;
    const int* lab = labels + (size_t)row * L;

    float o1[KPT];
    int lb[KPT];
    int localMax = -1;

    #pragma unroll
    for (int k = 0; k < KPT; ++k) {
        const int j = t + k * BDIM;
        float2 v = rowp[j];          // coalesced 8B/lane
        o1[k] = v.y;
        lb[k] = lab[j];              // coalesced 4B/lane
        // temp = argmax([v.x, v.y]) with first-occurrence tie-break:
        // temp==0 unless v.y > v.x strictly.
        if (!(v.y > v.x) && j > localMax) localMax = j;
    }

    // Block-wide max of last-zero index.
    __shared__ int smax[BDIM / 64];
    int m = localMax;
    #pragma unroll
    for (int off = 32; off; off >>= 1) m = max(m, __shfl_xor(m, off));
    if ((t & 63) == 0) smax[t >> 6] = m;
    __syncthreads();
    int idx = max(max(smax[0], smax[1]), max(smax[2], smax[3]));
    if (idx < 0) idx = L;   // all-ones row: mask everything (j<=L-1 identical)

    // Masked weighted sum: out1[j] * r1(j, label) for j <= idx.
    float sum = 0.0f;
    #pragma unroll
    for (int k = 0; k < KPT; ++k) {
        const int j = t + k * BDIM;
        if (j <= idx) {
            const float jf = (float)j;
            const float r1 = (lb[k] == 1) ? (-1.0f / log2f(jf + 2.0f))
                                          : ((jf + 1.0f) * (1.0f / ALPHA));
            sum += o1[k] * r1;
        }
    }

    // Block sum reduction.
    #pragma unroll
    for (int off = 32; off; off >>= 1) sum += __shfl_xor(sum, off);
    __shared__ float ssum[BDIM / 64];
    if ((t & 63) == 0) ssum[t >> 6] = sum;
    __syncthreads();
    if (t == 0) {
        const float tot = ssum[0] + ssum[1] + ssum[2] + ssum[3];
        atomicAdd(result, tot * (1.0f / 16384.0f));
    }
}

extern "C" void kernel_launch(void* const* d_in, const int* in_sizes, int n_in,
                              void* d_out, int out_size, void* d_ws, size_t ws_size,
                              hipStream_t stream) {
    const float* out_t = (const float*)d_in[0];   // [B, L, 2] fp32
    const int* labels = (const int*)d_in[1];      // [B, L] int
    float* result = (float*)d_out;                // scalar fp32

    const int B = in_sizes[1] / L;                // 16384

    hipMemsetAsync(result, 0, sizeof(float) * out_size, stream);
    bicut_loss_kernel<<<B, BDIM, 0, stream>>>(out_t, labels, result);
}

// Round 2
// 235.200 us; speedup vs baseline: 1.5946x; 1.5946x over previous
//
#include <hip/hip_runtime.h>

#define ALPHA 0.65f
#define L 1024
#define BDIM 256
#define KPT 4      // columns per thread: L / BDIM
#define GRID 2048  // 8 blocks/CU * 256 CUs

__global__ __launch_bounds__(BDIM) void bicut_partial_kernel(
    const float* __restrict__ out,     // [B, L, 2]
    const int* __restrict__ labels,    // [B, L]
    float* __restrict__ partials,      // [GRID]
    int B)
{
    const int t = threadIdx.x;
    __shared__ int smax[BDIM / 64];
    __shared__ float ssum[BDIM / 64];
    float acc = 0.0f;

    for (int row = blockIdx.x; row < B; row += GRID) {
        const float2* rowp = reinterpret_cast<const float2*>(out) + (size_t)row * L;
        const int* lab = labels + (size_t)row * L;

        float o1[KPT];
        int lb[KPT];
        int localMax = -1;

        #pragma unroll
        for (int k = 0; k < KPT; ++k) {
            const int j = t + k * BDIM;
            float2 v = rowp[j];          // coalesced 8B/lane
            o1[k] = v.y;
            lb[k] = lab[j];              // coalesced 4B/lane
            // temp = argmax([v.x, v.y]) with first-occurrence tie-break:
            // temp==0 unless v.y > v.x strictly. j increases with k.
            if (!(v.y > v.x)) localMax = j;
        }

        // Block-wide max of last-zero index.
        int m = localMax;
        #pragma unroll
        for (int off = 32; off; off >>= 1) m = max(m, __shfl_xor(m, off));
        if ((t & 63) == 0) smax[t >> 6] = m;
        __syncthreads();
        const int idx0 = max(max(smax[0], smax[1]), max(smax[2], smax[3]));
        const int idx = (idx0 < 0) ? L : idx0;  // all-ones row -> full mask

        // Masked weighted sum: out1[j] * r1(j, label) for j <= idx.
        float sum = 0.0f;
        #pragma unroll
        for (int k = 0; k < KPT; ++k) {
            const int j = t + k * BDIM;
            if (j <= idx) {
                const float jf = (float)j;
                const float r1 = (lb[k] == 1) ? (-1.0f / log2f(jf + 2.0f))
                                              : ((jf + 1.0f) * (1.0f / ALPHA));
                sum += o1[k] * r1;
            }
        }

        // Block sum reduction.
        #pragma unroll
        for (int off = 32; off; off >>= 1) sum += __shfl_xor(sum, off);
        if ((t & 63) == 0) ssum[t >> 6] = sum;
        __syncthreads();   // also protects smax/ssum reuse across row iterations
        if (t == 0) acc += ssum[0] + ssum[1] + ssum[2] + ssum[3];
    }

    if (t == 0) partials[blockIdx.x] = acc;
}

__global__ __launch_bounds__(BDIM) void bicut_final_kernel(
    const float* __restrict__ partials, float* __restrict__ result, int B)
{
    const int t = threadIdx.x;
    float s = 0.0f;
    for (int i = t; i < GRID; i += BDIM) s += partials[i];
    #pragma unroll
    for (int off = 32; off; off >>= 1) s += __shfl_xor(s, off);
    __shared__ float sh[BDIM / 64];
    if ((t & 63) == 0) sh[t >> 6] = s;
    __syncthreads();
    if (t == 0) result[0] = (sh[0] + sh[1] + sh[2] + sh[3]) * (1.0f / (float)B);
}

extern "C" void kernel_launch(void* const* d_in, const int* in_sizes, int n_in,
                              void* d_out, int out_size, void* d_ws, size_t ws_size,
                              hipStream_t stream) {
    const float* out_t = (const float*)d_in[0];   // [B, L, 2] fp32
    const int* labels = (const int*)d_in[1];      // [B, L] int
    float* result = (float*)d_out;                // scalar fp32
    float* partials = (float*)d_ws;               // GRID floats (8 KB)

    const int B = in_sizes[1] / L;                // 16384

    bicut_partial_kernel<<<GRID, BDIM, 0, stream>>>(out_t, labels, partials, B);
    bicut_final_kernel<<<1, BDIM, 0, stream>>>(partials, result, B);
}

// Round 3
// 234.182 us; speedup vs baseline: 1.6015x; 1.0043x over previous
//
#include <hip/hip_runtime.h>

#define ALPHA 0.65f
#define L 1024
#define BDIM 256
#define GRID 2048
#define WAVES_TOTAL (GRID * 4)   // 8192 waves, one row each per pass
#define ROWS_PER_WAVE 2          // 16384 rows total

__global__ __launch_bounds__(BDIM) void bicut_partial_kernel(
    const float* __restrict__ out,     // [B, L, 2]
    const int* __restrict__ labels,    // [B, L]
    float* __restrict__ partials,      // [WAVES_TOTAL]
    int B)
{
    const int t = threadIdx.x;
    const int lane = t & 63;
    const int gw = blockIdx.x * (BDIM / 64) + (t >> 6);

    // LDS table of r1 for label==1: -1/log2(j+2). Built once, then no
    // transcendentals in the hot loop. Read as float2 -> 2-way alias (free).
    __shared__ float tbl[L];
    #pragma unroll
    for (int k = 0; k < L / BDIM; ++k) {
        const int j = t + k * BDIM;
        tbl[j] = -1.0f / log2f((float)j + 2.0f);
    }
    __syncthreads();   // only barrier in the kernel

    const float inv_alpha = 1.0f / ALPHA;
    float acc = 0.0f;

    #pragma unroll
    for (int r = 0; r < ROWS_PER_WAVE; ++r) {
        const int row = gw + r * WAVES_TOTAL;
        if (row < B) {
            const float4* rowp = reinterpret_cast<const float4*>(out) + (size_t)row * (L / 2);
            const int2*  labp = reinterpret_cast<const int2*>(labels) + (size_t)row * (L / 2);

            float c[16];
            int localMax = -1;

            #pragma unroll
            for (int m = 0; m < 8; ++m) {
                const int e = lane + 64 * m;
                const float4 v = rowp[e];     // columns c0 (ch0,ch1), c0+1 (ch0,ch1)
                const int2 lb = labp[e];      // labels for columns c0, c0+1
                const int c0 = 2 * e;
                // temp = argmax([ch0, ch1]), first-occurrence tie-break:
                // zero unless ch1 > ch0 strictly. Columns increase with m.
                if (!(v.y > v.x)) localMax = c0;
                if (!(v.w > v.z)) localMax = c0 + 1;
                const float2 tv = *reinterpret_cast<const float2*>(&tbl[c0]);
                c[2 * m]     = v.y * (lb.x ? tv.x : (float)(c0 + 1) * inv_alpha);
                c[2 * m + 1] = v.w * (lb.y ? tv.y : (float)(c0 + 2) * inv_alpha);
            }

            // Wave-wide max of last-zero index (butterfly -> all lanes).
            int mx = localMax;
            #pragma unroll
            for (int off = 32; off; off >>= 1) mx = max(mx, __shfl_xor(mx, off));
            const int idx = (mx < 0) ? (L - 1) : mx;  // all-ones row: full mask

            // Masked sum of precomputed contributions.
            float s = 0.0f;
            #pragma unroll
            for (int m = 0; m < 8; ++m) {
                const int c0 = 2 * (lane + 64 * m);
                if (c0     <= idx) s += c[2 * m];
                if (c0 + 1 <= idx) s += c[2 * m + 1];
            }
            #pragma unroll
            for (int off = 32; off; off >>= 1) s += __shfl_xor(s, off);
            acc += s;   // uniform across lanes after butterfly
        }
    }

    if (lane == 0) partials[gw] = acc;
}

__global__ __launch_bounds__(BDIM) void bicut_final_kernel(
    const float* __restrict__ partials, float* __restrict__ result, int B)
{
    const int t = threadIdx.x;
    float s = 0.0f;
    #pragma unroll
    for (int i = 0; i < WAVES_TOTAL / BDIM; ++i) s += partials[t + i * BDIM];
    #pragma unroll
    for (int off = 32; off; off >>= 1) s += __shfl_xor(s, off);
    __shared__ float sh[BDIM / 64];
    if ((t & 63) == 0) sh[t >> 6] = s;
    __syncthreads();
    if (t == 0) result[0] = (sh[0] + sh[1] + sh[2] + sh[3]) / (float)B;
}

extern "C" void kernel_launch(void* const* d_in, const int* in_sizes, int n_in,
                              void* d_out, int out_size, void* d_ws, size_t ws_size,
                              hipStream_t stream) {
    const float* out_t = (const float*)d_in[0];   // [B, L, 2] fp32
    const int* labels = (const int*)d_in[1];      // [B, L] int
    float* result = (float*)d_out;                // scalar fp32
    float* partials = (float*)d_ws;               // 8192 floats (32 KB)

    const int B = in_sizes[1] / L;                // 16384

    bicut_partial_kernel<<<GRID, BDIM, 0, stream>>>(out_t, labels, partials, B);
    bicut_final_kernel<<<1, BDIM, 0, stream>>>(partials, result, B);
}

// Round 4
// 231.815 us; speedup vs baseline: 1.6179x; 1.0102x over previous
//
#include <hip/hip_runtime.h>

#define ALPHA 0.65f
#define L 1024
#define BDIM 256
#define WPB (BDIM / 64)   // 4 waves per block
#define NBLK 4096         // 16384 waves, one row per wave

__global__ __launch_bounds__(BDIM) void bicut_partial_kernel(
    const float4* __restrict__ out4,   // [B, 512] float4 view of [B, L, 2]
    const int2*  __restrict__ lab2,    // [B, 512] int2 view of [B, L]
    float* __restrict__ partials,      // [B]
    int B)
{
    const int t = threadIdx.x;
    const int lane = t & 63;

    // r1 table for label==1: -1/log2(j+2). Built once per block.
    __shared__ float tbl[L];
    #pragma unroll
    for (int k = 0; k < L / BDIM; ++k) {
        const int j = t + k * BDIM;
        tbl[j] = -1.0f / log2f((float)j + 2.0f);
    }
    __syncthreads();

    const int row = blockIdx.x * WPB + (t >> 6);
    const float4* rp = out4 + (size_t)row * (L / 2);
    const int2*  lp = lab2 + (size_t)row * (L / 2);

    // ---- load phase: 16 independent coalesced loads, all in flight ----
    float4 v[8];
    int2 lb[8];
    #pragma unroll
    for (int m = 0; m < 8; ++m) v[m] = rp[lane + 64 * m];
    #pragma unroll
    for (int m = 0; m < 8; ++m) lb[m] = lp[lane + 64 * m];

    // ---- last-zero index: temp==1 iff ch1 > ch0 strictly (argmax tie->0) ----
    int localMax = -1;
    #pragma unroll
    for (int m = 0; m < 8; ++m) {
        const int c0 = 2 * (lane + 64 * m);   // columns increase with m
        if (!(v[m].y > v[m].x)) localMax = c0;
        if (!(v[m].w > v[m].z)) localMax = c0 + 1;
    }
    int mx = localMax;
    #pragma unroll
    for (int off = 32; off; off >>= 1) mx = max(mx, __shfl_xor(mx, off));
    const int idx = (mx < 0) ? (L - 1) : mx;  // all-ones row: full mask

    // ---- masked weighted sum ----
    const float inv_alpha = 1.0f / ALPHA;
    float s = 0.0f;
    #pragma unroll
    for (int m = 0; m < 8; ++m) {
        const int c0 = 2 * (lane + 64 * m);
        const float2 tv = *reinterpret_cast<const float2*>(&tbl[c0]);
        const float r0 = lb[m].x ? tv.x : (float)(c0 + 1) * inv_alpha;
        const float r1 = lb[m].y ? tv.y : (float)(c0 + 2) * inv_alpha;
        if (c0     <= idx) s += v[m].y * r0;
        if (c0 + 1 <= idx) s += v[m].w * r1;
    }
    #pragma unroll
    for (int off = 32; off; off >>= 1) s += __shfl_xor(s, off);
    if (lane == 0) partials[row] = s;
}

__global__ __launch_bounds__(BDIM) void bicut_final_kernel(
    const float4* __restrict__ p4, float* __restrict__ result, int B)
{
    const int t = threadIdx.x;
    float s = 0.0f;
    #pragma unroll
    for (int i = 0; i < 16; ++i) {   // 16384 floats = 4096 float4
        const float4 v = p4[t + i * BDIM];
        s += (v.x + v.y) + (v.z + v.w);
    }
    #pragma unroll
    for (int off = 32; off; off >>= 1) s += __shfl_xor(s, off);
    __shared__ float sh[BDIM / 64];
    if ((t & 63) == 0) sh[t >> 6] = s;
    __syncthreads();
    if (t == 0) result[0] = ((sh[0] + sh[1]) + (sh[2] + sh[3])) / (float)B;
}

extern "C" void kernel_launch(void* const* d_in, const int* in_sizes, int n_in,
                              void* d_out, int out_size, void* d_ws, size_t ws_size,
                              hipStream_t stream) {
    const float4* out4 = (const float4*)d_in[0];  // [B, L, 2] fp32
    const int2* lab2 = (const int2*)d_in[1];      // [B, L] int
    float* result = (float*)d_out;                // scalar fp32
    float* partials = (float*)d_ws;               // B floats (64 KB)

    const int B = in_sizes[1] / L;                // 16384

    bicut_partial_kernel<<<NBLK, BDIM, 0, stream>>>(out4, lab2, partials, B);
    bicut_final_kernel<<<1, BDIM, 0, stream>>>((const float4*)partials, result, B);
}

// Round 5
// 214.811 us; speedup vs baseline: 1.7460x; 1.0792x over previous
//
#include <hip/hip_runtime.h>

#define ALPHA 0.65f
#define L 1024
#define BDIM 256
#define WPB (BDIM / 64)   // 4 waves per block
#define NBLK 4096         // 16384 waves, one row per wave

typedef float v4f __attribute__((ext_vector_type(4)));
typedef int   v2i __attribute__((ext_vector_type(2)));

__global__ __launch_bounds__(BDIM) void bicut_partial_kernel(
    const v4f* __restrict__ out4,      // [B, 512] float4 view of [B, L, 2]
    const v2i* __restrict__ lab2,      // [B, 512] int2 view of [B, L]
    float* __restrict__ partials,      // [B]
    int B)
{
    const int t = threadIdx.x;
    const int lane = t & 63;

    // r1 table for label==1: -1/log2(j+2). Built once per block.
    __shared__ float tbl[L];
    #pragma unroll
    for (int k = 0; k < L / BDIM; ++k) {
        const int j = t + k * BDIM;
        tbl[j] = -1.0f / log2f((float)j + 2.0f);
    }
    __syncthreads();

    const int row = blockIdx.x * WPB + (t >> 6);
    const v4f* rp = out4 + (size_t)row * (L / 2);
    const v2i* lp = lab2 + (size_t)row * (L / 2);

    // ---- load phase: 16 independent coalesced NT loads (bypass L2/L3) ----
    v4f v[8];
    v2i lb[8];
    #pragma unroll
    for (int m = 0; m < 8; ++m) v[m] = __builtin_nontemporal_load(&rp[lane + 64 * m]);
    #pragma unroll
    for (int m = 0; m < 8; ++m) lb[m] = __builtin_nontemporal_load(&lp[lane + 64 * m]);

    // ---- last-zero index: temp==1 iff ch1 > ch0 strictly (argmax tie->0) ----
    int localMax = -1;
    #pragma unroll
    for (int m = 0; m < 8; ++m) {
        const int c0 = 2 * (lane + 64 * m);   // columns increase with m
        if (!(v[m].y > v[m].x)) localMax = c0;
        if (!(v[m].w > v[m].z)) localMax = c0 + 1;
    }
    int mx = localMax;
    #pragma unroll
    for (int off = 32; off; off >>= 1) mx = max(mx, __shfl_xor(mx, off));
    const int idx = (mx < 0) ? (L - 1) : mx;  // all-ones row: full mask

    // ---- masked weighted sum ----
    const float inv_alpha = 1.0f / ALPHA;
    float s = 0.0f;
    #pragma unroll
    for (int m = 0; m < 8; ++m) {
        const int c0 = 2 * (lane + 64 * m);
        const float2 tv = *reinterpret_cast<const float2*>(&tbl[c0]);
        const float r0 = lb[m].x ? tv.x : (float)(c0 + 1) * inv_alpha;
        const float r1 = lb[m].y ? tv.y : (float)(c0 + 2) * inv_alpha;
        if (c0     <= idx) s += v[m].y * r0;
        if (c0 + 1 <= idx) s += v[m].w * r1;
    }
    #pragma unroll
    for (int off = 32; off; off >>= 1) s += __shfl_xor(s, off);
    if (lane == 0) partials[row] = s;
}

__global__ __launch_bounds__(BDIM) void bicut_final_kernel(
    const float4* __restrict__ p4, float* __restrict__ result, int B)
{
    const int t = threadIdx.x;
    float s = 0.0f;
    #pragma unroll
    for (int i = 0; i < 16; ++i) {   // 16384 floats = 4096 float4
        const float4 v = p4[t + i * BDIM];
        s += (v.x + v.y) + (v.z + v.w);
    }
    #pragma unroll
    for (int off = 32; off; off >>= 1) s += __shfl_xor(s, off);
    __shared__ float sh[BDIM / 64];
    if ((t & 63) == 0) sh[t >> 6] = s;
    __syncthreads();
    if (t == 0) result[0] = ((sh[0] + sh[1]) + (sh[2] + sh[3])) / (float)B;
}

extern "C" void kernel_launch(void* const* d_in, const int* in_sizes, int n_in,
                              void* d_out, int out_size, void* d_ws, size_t ws_size,
                              hipStream_t stream) {
    const v4f* out4 = (const v4f*)d_in[0];        // [B, L, 2] fp32
    const v2i* lab2 = (const v2i*)d_in[1];        // [B, L] int
    float* result = (float*)d_out;                // scalar fp32
    float* partials = (float*)d_ws;               // B floats (64 KB)

    const int B = in_sizes[1] / L;                // 16384

    bicut_partial_kernel<<<NBLK, BDIM, 0, stream>>>(out4, lab2, partials, B);
    bicut_final_kernel<<<1, BDIM, 0, stream>>>((const float4*)partials, result, B);
}